// Round 3
// baseline (109.510 us; speedup 1.0000x reference)
//
#include <hip/hip_runtime.h>

#define IMG_H 1024
#define IMG_W 1024
#define TILES 16                 // 16x16 output tiles per block (= 32x32 pixels)
#define NPJ 17                   // patches per dim incl. halo
#define NPATCH (NPJ * NPJ)       // 289
#define NCJ 18                   // conv blocks per dim incl. halo
#define NCB (NCJ * NCJ)          // 324 distinct 2x2 conv blocks
#define PSTR 20                  // padded floats per patch in LDS (80 B, 16B-aligned)

static __device__ __forceinline__ int iclamp(int v, int lo, int hi) {
    return v < lo ? lo : (v > hi ? hi : v);
}

__global__ __launch_bounds__(256) void ae_fused(
    const float* __restrict__ img,
    const float* __restrict__ w_conv,
    const float* __restrict__ b_conv,
    const float* __restrict__ W_b,
    const float* __restrict__ b_b,
    const float* __restrict__ W_d,
    const float* __restrict__ b_d,
    float* __restrict__ out)
{
    __shared__ __align__(16) float dec[NPATCH * PSTR];   // 23120 B
    __shared__ __align__(8)  float2 convs[NCB];          //  2592 B

    const int t  = threadIdx.x;
    const int n0 = blockIdx.x * TILES;   // tile col base
    const int m0 = blockIdx.y * TILES;   // tile row base
    const int b  = blockIdx.z;

    // uniform weights (broadcast loads)
    float wc[2][4], wd[2][4], wb[2][2];
    #pragma unroll
    for (int c = 0; c < 2; ++c) {
        #pragma unroll
        for (int q = 0; q < 4; ++q) {
            wc[c][q] = w_conv[c * 4 + q];
            wd[c][q] = W_d[c * 4 + q];
        }
    }
    wb[0][0] = W_b[0]; wb[0][1] = W_b[1];
    wb[1][0] = W_b[2]; wb[1][1] = W_b[3];
    const float bc0 = b_conv[0], bc1 = b_conv[1];
    const float bb0 = b_b[0],   bb1 = b_b[1];
    const float bd  = b_d[0];

    const float* imgb = img + (size_t)b * IMG_H * IMG_W;

    // ---- stage 0: each distinct 2x2 conv block computed ONCE (was 4x per patch) ----
    // Block (J,K) reads img[2J..2J+1][2K..2K+1]; clamped edge blocks feed only
    // invalid patches, which stage 1 zeroes anyway.
    #pragma unroll
    for (int it = 0; it < 2; ++it) {
        const int cb = t + it * 256;
        if (cb < NCB) {
            const int cj = cb / NCJ;
            const int ck = cb - cj * NCJ;
            const int J = iclamp(m0 - 1 + cj, 0, 511);
            const int K = iclamp(n0 - 1 + ck, 0, 511);
            const float* base = imgb + (size_t)(2 * J) * IMG_W + 2 * K;
            const float2 r0 = *(const float2*)(base);
            const float2 r1 = *(const float2*)(base + IMG_W);
            const float s0 = r0.x * wc[0][0] + r0.y * wc[0][1] + r1.x * wc[0][2] + r1.y * wc[0][3] + bc0;
            const float s1 = r0.x * wc[1][0] + r0.y * wc[1][1] + r1.x * wc[1][2] + r1.y * wc[1][3] + bc1;
            convs[cb] = make_float2(fmaxf(s0, 0.0f), fmaxf(s1, 0.0f));
        }
    }
    __syncthreads();

    // ---- stage 1: one thread per patch — argmax/bottleneck/decode/sigmoid -> LDS ----
    const float sc = 1.0f / (1.0f + __expf(-bd));   // inactive-quadrant value (0*w+0*w+bd == bd)
    #pragma unroll
    for (int it = 0; it < 2; ++it) {
        const int lp = t + it * 256;
        if (lp < NPATCH) {
            const int lpj = lp / NPJ;
            const int lpk = lp - lpj * NPJ;
            const int j = m0 - 1 + lpj;
            const int k = n0 - 1 + lpk;
            float* d = &dec[lp * PSTR];
            if (j >= 0 && j <= 510 && k >= 0 && k <= 510) {
                // quadrant (jj,kk) of this patch == conv block (lpj+jj, lpk+kk)
                const int cbase = lpj * NCJ + lpk;
                const float2 c00 = convs[cbase];
                const float2 c01 = convs[cbase + 1];
                const float2 c10 = convs[cbase + NCJ];
                const float2 c11 = convs[cbase + NCJ + 1];
                const float v0[4] = { c00.x, c01.x, c10.x, c11.x };
                const float v1[4] = { c00.y, c01.y, c10.y, c11.y };

                // first-occurrence argmax (jnp tie rule)
                int i0 = 0, i1 = 0;
                float mx0 = v0[0], mx1 = v1[0];
                #pragma unroll
                for (int q = 1; q < 4; ++q) {
                    if (v0[q] > mx0) { mx0 = v0[q]; i0 = q; }
                    if (v1[q] > mx1) { mx1 = v1[q]; i1 = q; }
                }
                // bottleneck
                const float z0 = fmaxf(mx0 * wb[0][0] + mx1 * wb[0][1] + bb0, 0.0f);
                const float z1 = fmaxf(mx0 * wb[1][0] + mx1 * wb[1][1] + bb1, 0.0f);

                // fill all quads with the constant, then overwrite the active one(s)
                const float4 cq = make_float4(sc, sc, sc, sc);
                #pragma unroll
                for (int qd = 0; qd < 4; ++qd) *(float4*)(d + qd * 4) = cq;

                {   // quadrant holding ch0 argmax
                    const float g0 = z0;
                    const float g1 = (i1 == i0) ? z1 : 0.0f;
                    float4 q;
                    q.x = 1.0f / (1.0f + __expf(-(g0 * wd[0][0] + g1 * wd[1][0] + bd)));
                    q.y = 1.0f / (1.0f + __expf(-(g0 * wd[0][1] + g1 * wd[1][1] + bd)));
                    q.z = 1.0f / (1.0f + __expf(-(g0 * wd[0][2] + g1 * wd[1][2] + bd)));
                    q.w = 1.0f / (1.0f + __expf(-(g0 * wd[0][3] + g1 * wd[1][3] + bd)));
                    *(float4*)(d + i0 * 4) = q;
                }
                {   // quadrant holding ch1 argmax (identical bits if i1==i0)
                    const float g0 = (i0 == i1) ? z0 : 0.0f;
                    const float g1 = z1;
                    float4 q;
                    q.x = 1.0f / (1.0f + __expf(-(g0 * wd[0][0] + g1 * wd[1][0] + bd)));
                    q.y = 1.0f / (1.0f + __expf(-(g0 * wd[0][1] + g1 * wd[1][1] + bd)));
                    q.z = 1.0f / (1.0f + __expf(-(g0 * wd[0][2] + g1 * wd[1][2] + bd)));
                    q.w = 1.0f / (1.0f + __expf(-(g0 * wd[0][3] + g1 * wd[1][3] + bd)));
                    *(float4*)(d + i1 * 4) = q;
                }
            } else {
                const float4 zq = make_float4(0.0f, 0.0f, 0.0f, 0.0f);
                #pragma unroll
                for (int qd = 0; qd < 4; ++qd) *(float4*)(d + qd * 4) = zq;
            }
        }
    }
    __syncthreads();

    // ---- stage 2: gather 4 quadrants per output 2x2 tile ----
    const int ty = t >> 4, tx = t & 15;
    const int m = m0 + ty, n = n0 + tx;
    float a0 = 0.f, a1 = 0.f, a2 = 0.f, a3 = 0.f;
    #pragma unroll
    for (int a = 0; a < 2; ++a) {        // a=0: patch j=m-1 (quad row 1); a=1: j=m (quad row 0)
        #pragma unroll
        for (int e = 0; e < 2; ++e) {    // e=0: patch k=n-1 (quad col 1); e=1: k=n (quad col 0)
            const int lp = (ty + a) * NPJ + (tx + e);
            const int qd = (1 - a) * 2 + (1 - e);
            const float4 q = *(const float4*)(dec + lp * PSTR + qd * 4);
            a0 += q.x; a1 += q.y; a2 += q.z; a3 += q.w;
        }
    }
    const float rcnt = 1.0f / (float)(((m >= 1) + (m <= 510)) * ((n >= 1) + (n <= 510)));
    float* outb = out + (size_t)b * IMG_H * IMG_W;
    *(float2*)(outb + (size_t)(2 * m) * IMG_W + 2 * n)     = make_float2(a0 * rcnt, a1 * rcnt);
    *(float2*)(outb + (size_t)(2 * m + 1) * IMG_W + 2 * n) = make_float2(a2 * rcnt, a3 * rcnt);
}

extern "C" void kernel_launch(void* const* d_in, const int* in_sizes, int n_in,
                              void* d_out, int out_size, void* d_ws, size_t ws_size,
                              hipStream_t stream) {
    const float* img    = (const float*)d_in[0];
    const float* w_conv = (const float*)d_in[1];
    const float* b_conv = (const float*)d_in[2];
    const float* W_b    = (const float*)d_in[3];
    const float* b_b    = (const float*)d_in[4];
    const float* W_d    = (const float*)d_in[5];
    const float* b_d    = (const float*)d_in[6];
    float* out = (float*)d_out;

    dim3 block(256, 1, 1);
    dim3 grid(512 / TILES, 512 / TILES, 8);   // 32 x 32 x 8 blocks
    ae_fused<<<grid, block, 0, stream>>>(img, w_conv, b_conv, W_b, b_b, W_d, b_d, out);
}

// Round 4
// 107.893 us; speedup vs baseline: 1.0150x; 1.0150x over previous
//
#include <hip/hip_runtime.h>

#define IMG_H 1024
#define IMG_W 1024
#define TILES 16                 // 16x16 output tiles per block (= 32x32 pixels)
#define NPJ 17                   // patches per dim incl. halo
#define NPATCH (NPJ * NPJ)       // 289
#define NCJ 18                   // conv blocks per dim incl. halo
#define NCB (NCJ * NCJ)          // 324 distinct 2x2 conv blocks
#define PSTR 20                  // padded floats per patch in LDS (80 B, 16B-aligned)
#define RAW_W 40                 // raw tile: 36 rows x 40 cols (float), 16B-aligned rows
#define RAW_H 36

static __device__ __forceinline__ int iclamp(int v, int lo, int hi) {
    return v < lo ? lo : (v > hi ? hi : v);
}

__global__ __launch_bounds__(256) void ae_fused(
    const float* __restrict__ img,
    const float* __restrict__ w_conv,
    const float* __restrict__ b_conv,
    const float* __restrict__ W_b,
    const float* __restrict__ b_b,
    const float* __restrict__ W_d,
    const float* __restrict__ b_d,
    float* __restrict__ out)
{
    // raw (5760 B, dead after stage B) aliases dec (23120 B, born in stage 1)
    __shared__ __align__(16) float shbuf[NPATCH * PSTR];   // 23120 B
    __shared__ __align__(8)  float2 convs[NCB];            //  2592 B
    float* raw = shbuf;
    float* dec = shbuf;

    const int t  = threadIdx.x;
    const int n0 = blockIdx.x * TILES;   // tile col base
    const int m0 = blockIdx.y * TILES;   // tile row base
    const int b  = blockIdx.z;

    // uniform weights (broadcast loads)
    float wc[2][4], wd[2][4], wb[2][2];
    #pragma unroll
    for (int c = 0; c < 2; ++c) {
        #pragma unroll
        for (int q = 0; q < 4; ++q) {
            wc[c][q] = w_conv[c * 4 + q];
            wd[c][q] = W_d[c * 4 + q];
        }
    }
    wb[0][0] = W_b[0]; wb[0][1] = W_b[1];
    wb[1][0] = W_b[2]; wb[1][1] = W_b[3];
    const float bc0 = b_conv[0], bc1 = b_conv[1];
    const float bb0 = b_b[0],   bb1 = b_b[1];
    const float bd  = b_d[0];

    const float* imgb = img + (size_t)b * IMG_H * IMG_W;

    // ---- stage A: coalesced b128 staging of the 36x40 raw region ----
    // rows pr0..pr0+35, cols cb4..cb4+39 (clamped float4s feed only invalid
    // border patches, which stage 1 zeroes)
    const int pr0 = 2 * m0 - 2;
    const int cb4 = 2 * n0 - 4;          // multiple of 4 -> 16B aligned
    #pragma unroll
    for (int it = 0; it < 2; ++it) {
        const int idx = t + it * 256;
        if (idx < RAW_H * 10) {          // 360 float4 loads
            const int r  = idx / 10;
            const int c4 = idx - r * 10;
            const int gr = iclamp(pr0 + r, 0, IMG_H - 1);
            const int gc = iclamp(cb4 + 4 * c4, 0, IMG_W - 4);
            const float4 v = *(const float4*)(imgb + (size_t)gr * IMG_W + gc);
            *(float4*)(raw + r * RAW_W + 4 * c4) = v;
        }
    }
    __syncthreads();

    // ---- stage B: each distinct 2x2 conv block once, from LDS raw ----
    // conv block (cj,ck): global rows 2(m0-1+cj).., cols 2(n0-1+ck)..
    // -> raw local row 2*cj, local col 2*ck + 2
    #pragma unroll
    for (int it = 0; it < 2; ++it) {
        const int cb = t + it * 256;
        if (cb < NCB) {
            const int cj = cb / NCJ;
            const int ck = cb - cj * NCJ;
            const float* rp = raw + (2 * cj) * RAW_W + 2 * ck + 2;
            const float2 r0 = *(const float2*)(rp);
            const float2 r1 = *(const float2*)(rp + RAW_W);
            const float s0 = r0.x * wc[0][0] + r0.y * wc[0][1] + r1.x * wc[0][2] + r1.y * wc[0][3] + bc0;
            const float s1 = r0.x * wc[1][0] + r0.y * wc[1][1] + r1.x * wc[1][2] + r1.y * wc[1][3] + bc1;
            convs[cb] = make_float2(fmaxf(s0, 0.0f), fmaxf(s1, 0.0f));
        }
    }
    __syncthreads();   // also protects raw->dec aliasing

    // ---- stage 1: one thread per patch — argmax/bottleneck/decode/sigmoid -> LDS ----
    const float sc = 1.0f / (1.0f + __expf(-bd));   // inactive quadrant (0*w+0*w+bd == bd)
    #pragma unroll
    for (int it = 0; it < 2; ++it) {
        const int lp = t + it * 256;
        if (lp < NPATCH) {
            const int lpj = lp / NPJ;
            const int lpk = lp - lpj * NPJ;
            const int j = m0 - 1 + lpj;
            const int k = n0 - 1 + lpk;
            float* d = &dec[lp * PSTR];
            if (j >= 0 && j <= 510 && k >= 0 && k <= 510) {
                const int cbase = lpj * NCJ + lpk;
                const float2 c00 = convs[cbase];
                const float2 c01 = convs[cbase + 1];
                const float2 c10 = convs[cbase + NCJ];
                const float2 c11 = convs[cbase + NCJ + 1];
                const float v0[4] = { c00.x, c01.x, c10.x, c11.x };
                const float v1[4] = { c00.y, c01.y, c10.y, c11.y };

                int i0 = 0, i1 = 0;
                float mx0 = v0[0], mx1 = v1[0];
                #pragma unroll
                for (int q = 1; q < 4; ++q) {
                    if (v0[q] > mx0) { mx0 = v0[q]; i0 = q; }
                    if (v1[q] > mx1) { mx1 = v1[q]; i1 = q; }
                }
                const float z0 = fmaxf(mx0 * wb[0][0] + mx1 * wb[0][1] + bb0, 0.0f);
                const float z1 = fmaxf(mx0 * wb[1][0] + mx1 * wb[1][1] + bb1, 0.0f);

                const float4 cq = make_float4(sc, sc, sc, sc);
                #pragma unroll
                for (int qd = 0; qd < 4; ++qd) *(float4*)(d + qd * 4) = cq;

                {   // quadrant holding ch0 argmax
                    const float g0 = z0;
                    const float g1 = (i1 == i0) ? z1 : 0.0f;
                    float4 q;
                    q.x = 1.0f / (1.0f + __expf(-(g0 * wd[0][0] + g1 * wd[1][0] + bd)));
                    q.y = 1.0f / (1.0f + __expf(-(g0 * wd[0][1] + g1 * wd[1][1] + bd)));
                    q.z = 1.0f / (1.0f + __expf(-(g0 * wd[0][2] + g1 * wd[1][2] + bd)));
                    q.w = 1.0f / (1.0f + __expf(-(g0 * wd[0][3] + g1 * wd[1][3] + bd)));
                    *(float4*)(d + i0 * 4) = q;
                }
                {   // quadrant holding ch1 argmax (identical bits if i1==i0)
                    const float g0 = (i0 == i1) ? z0 : 0.0f;
                    const float g1 = z1;
                    float4 q;
                    q.x = 1.0f / (1.0f + __expf(-(g0 * wd[0][0] + g1 * wd[1][0] + bd)));
                    q.y = 1.0f / (1.0f + __expf(-(g0 * wd[0][1] + g1 * wd[1][1] + bd)));
                    q.z = 1.0f / (1.0f + __expf(-(g0 * wd[0][2] + g1 * wd[1][2] + bd)));
                    q.w = 1.0f / (1.0f + __expf(-(g0 * wd[0][3] + g1 * wd[1][3] + bd)));
                    *(float4*)(d + i1 * 4) = q;
                }
            } else {
                const float4 zq = make_float4(0.0f, 0.0f, 0.0f, 0.0f);
                #pragma unroll
                for (int qd = 0; qd < 4; ++qd) *(float4*)(d + qd * 4) = zq;
            }
        }
    }
    __syncthreads();

    // ---- stage 2: gather 4 quadrants per output 2x2 tile ----
    const int ty = t >> 4, tx = t & 15;
    const int m = m0 + ty, n = n0 + tx;
    float a0 = 0.f, a1 = 0.f, a2 = 0.f, a3 = 0.f;
    #pragma unroll
    for (int a = 0; a < 2; ++a) {        // a=0: patch j=m-1 (quad row 1); a=1: j=m (quad row 0)
        #pragma unroll
        for (int e = 0; e < 2; ++e) {    // e=0: patch k=n-1 (quad col 1); e=1: k=n (quad col 0)
            const int lp = (ty + a) * NPJ + (tx + e);
            const int qd = (1 - a) * 2 + (1 - e);
            const float4 q = *(const float4*)(dec + lp * PSTR + qd * 4);
            a0 += q.x; a1 += q.y; a2 += q.z; a3 += q.w;
        }
    }
    const float rcnt = 1.0f / (float)(((m >= 1) + (m <= 510)) * ((n >= 1) + (n <= 510)));
    float* outb = out + (size_t)b * IMG_H * IMG_W;
    *(float2*)(outb + (size_t)(2 * m) * IMG_W + 2 * n)     = make_float2(a0 * rcnt, a1 * rcnt);
    *(float2*)(outb + (size_t)(2 * m + 1) * IMG_W + 2 * n) = make_float2(a2 * rcnt, a3 * rcnt);
}

extern "C" void kernel_launch(void* const* d_in, const int* in_sizes, int n_in,
                              void* d_out, int out_size, void* d_ws, size_t ws_size,
                              hipStream_t stream) {
    const float* img    = (const float*)d_in[0];
    const float* w_conv = (const float*)d_in[1];
    const float* b_conv = (const float*)d_in[2];
    const float* W_b    = (const float*)d_in[3];
    const float* b_b    = (const float*)d_in[4];
    const float* W_d    = (const float*)d_in[5];
    const float* b_d    = (const float*)d_in[6];
    float* out = (float*)d_out;

    dim3 block(256, 1, 1);
    dim3 grid(512 / TILES, 512 / TILES, 8);   // 32 x 32 x 8 blocks
    ae_fused<<<grid, block, 0, stream>>>(img, w_conv, b_conv, W_b, b_b, W_d, b_d, out);
}